// Round 10
// baseline (494.359 us; speedup 1.0000x reference)
//
#include <hip/hip_runtime.h>
#include <math.h>

#define NRES 256
#define NZK  129                   // NRES/2 + 1
#define NLINE_XY (NRES * NRES)     // 65536 z-lines
#define STRX (NRES * NZK)          // 33024 : float2 stride between x-planes
#define NSPEC (NRES * NRES * NZK)  // 8454144 spectral elements
#define TWO_PI 6.283185307179586f
#define NBIN 65536                 // (ix,iy) sort bins

// ---------------------------------------------------------------------------
// 16-point DFT in registers, radix-2 Stockham, fully unrolled.
// y[c] = sum_j v[j] * e^{sgn*2*pi*i*j*c/16}. Result in v, natural order.
// ---------------------------------------------------------------------------
__device__ __forceinline__ void dft16(float2* v, float sgn) {
    const float C16[8] = {1.f, 0.923879532511287f, 0.707106781186548f, 0.382683432365090f,
                          0.f, -0.382683432365090f, -0.707106781186548f, -0.923879532511287f};
    const float S16[8] = {0.f, 0.382683432365090f, 0.707106781186548f, 0.923879532511287f,
                          1.f, 0.923879532511287f, 0.707106781186548f, 0.382683432365090f};
    float2 t[16];
    float2* src = v;
    float2* dst = t;
#pragma unroll
    for (int s = 0; s < 4; ++s) {
        const int st = 1 << s;
#pragma unroll
        for (int bb = 0; bb < 8; ++bb) {
            const int q = bb & (st - 1);
            const int p = bb >> s;
            const int m = p << s;               // twiddle index into C16/S16
            float2 a = src[q + st * p];
            float2 b = src[q + st * p + 8];     // st*(p + nt/2) = st*p + 8
            float cw = C16[m], sw = sgn * S16[m];
            float ar = a.x - b.x, ai = a.y - b.y;
            dst[q + st * 2 * p]       = make_float2(a.x + b.x, a.y + b.y);
            dst[q + st * (2 * p + 1)] = make_float2(ar * cw - ai * sw, ar * sw + ai * cw);
        }
        float2* tmp = src; src = dst; dst = tmp;
    }
    // 4 stages (even) -> result back in v
}

// 16-wide tile variant (z/x kernels): J[c][tx][tl], tl in [0,16)
__device__ __forceinline__ void twiddle_store(float2* J, const float2* v, int tl, int tx, float sgn) {
    float s1, c1;
    __sincosf(sgn * (TWO_PI / 256.f) * (float)tx, &s1, &c1);
    float wr = 1.f, wi = 0.f;
#pragma unroll
    for (int c = 0; c < 16; ++c) {
        float2 a = v[c];
        J[(c * 16 + tx) * 16 + tl] = make_float2(a.x * wr - a.y * wi, a.x * wi + a.y * wr);
        float nwr = wr * c1 - wi * s1;
        wi = wr * s1 + wi * c1;
        wr = nwr;
    }
}

// 32-wide tile variant (y kernels): J[c][tx][tl], tl in [0,32)
__device__ __forceinline__ void twiddle_store32(float2* J, const float2* v, int tl, int tx, float sgn) {
    float s1, c1;
    __sincosf(sgn * (TWO_PI / 256.f) * (float)tx, &s1, &c1);
    float wr = 1.f, wi = 0.f;
#pragma unroll
    for (int c = 0; c < 16; ++c) {
        float2 a = v[c];
        J[(c * 16 + tx) * 32 + tl] = make_float2(a.x * wr - a.y * wi, a.x * wi + a.y * wr);
        float nwr = wr * c1 - wi * s1;
        wi = wr * s1 + wi * c1;
        wr = nwr;
    }
}

// ---------------------------------------------------------------------------
// Point sort by (ix,iy) cell — counting sort, 65536 bins. Scattered atomics
// over the full 67 MB grid were ~90 us across the 3 rasters; sorted points
// give each wave a ~2x44 KB atomic window (L2-resident).
// NOTE: sort scratch lives in `out` and is DEAD after kfft_z_c2r overwrites
// out — kinterp must read the ORIGINAL V (round-9 post-mortem).
// ---------------------------------------------------------------------------
__device__ __forceinline__ int cell_of(const float* __restrict__ pts, int p) {
    float px = pts[p * 3 + 0] * (float)NRES;
    float py = pts[p * 3 + 1] * (float)NRES;
    int ix = ((int)floorf(px)) & 255;
    int iy = ((int)floorf(py)) & 255;
    return (ix << 8) | iy;
}

__global__ void khist(const float* __restrict__ pts, int* __restrict__ hist, int P) {
    int p = blockIdx.x * blockDim.x + threadIdx.x;
    if (p >= P) return;
    atomicAdd(&hist[cell_of(pts, p)], 1);
}

// Exclusive prefix over 65536 bins; 1 block x 1024 threads, 64 bins/thread.
__global__ __launch_bounds__(1024) void kscan(const int* __restrict__ hist,
                                              int* __restrict__ offs) {
    __shared__ int part[1024];
    const int tid = threadIdx.x;
    const int base = tid * 64;
    int s = 0;
#pragma unroll
    for (int i = 0; i < 64; ++i) s += hist[base + i];
    part[tid] = s;
    __syncthreads();
    for (int off = 1; off < 1024; off <<= 1) {
        int v = (tid >= off) ? part[tid - off] : 0;
        __syncthreads();
        part[tid] += v;
        __syncthreads();
    }
    int run = (tid > 0) ? part[tid - 1] : 0;
#pragma unroll
    for (int i = 0; i < 64; ++i) {
        offs[base + i] = run;
        run += hist[base + i];
    }
}

__global__ void kscatter(const float* __restrict__ pts, const float* __restrict__ vals,
                         int* __restrict__ offs, float* __restrict__ spts,
                         float* __restrict__ svals, int P) {
    int p = blockIdx.x * blockDim.x + threadIdx.x;
    if (p >= P) return;
    int idx = atomicAdd(&offs[cell_of(pts, p)], 1);
    spts[idx * 3 + 0] = pts[p * 3 + 0];
    spts[idx * 3 + 1] = pts[p * 3 + 1];
    spts[idx * 3 + 2] = pts[p * 3 + 2];
    svals[idx * 3 + 0] = vals[p * 3 + 0];
    svals[idx * 3 + 1] = vals[p * 3 + 1];
    svals[idx * 3 + 2] = vals[p * 3 + 2];
}

// ---------------------------------------------------------------------------
// Rasterize channel c into real grid R (points pre-sorted by (ix,iy)).
// ---------------------------------------------------------------------------
__global__ void kraster(const float* __restrict__ pts, const float* __restrict__ vals,
                        float* __restrict__ R, int P, int c) {
    int p = blockIdx.x * blockDim.x + threadIdx.x;
    if (p >= P) return;
    float px = pts[p * 3 + 0] * (float)NRES;
    float py = pts[p * 3 + 1] * (float)NRES;
    float pz = pts[p * 3 + 2] * (float)NRES;
    float fx0 = floorf(px), fy0 = floorf(py), fz0 = floorf(pz);
    int ix = ((int)fx0) & 255, iy = ((int)fy0) & 255, iz = ((int)fz0) & 255;
    float tx = px - fx0, ty = py - fy0, tz = pz - fz0;
    float v = vals[p * 3 + c];
    int ix1 = (ix + 1) & 255, iy1 = (iy + 1) & 255, iz1 = (iz + 1) & 255;
    float wx0 = 1.f - tx, wy0 = 1.f - ty, wz0 = 1.f - tz;
    atomicAdd(&R[((ix  * NRES + iy ) * NRES) + iz ], v * wx0 * wy0 * wz0);
    atomicAdd(&R[((ix  * NRES + iy ) * NRES) + iz1], v * wx0 * wy0 * tz );
    atomicAdd(&R[((ix  * NRES + iy1) * NRES) + iz ], v * wx0 * ty  * wz0);
    atomicAdd(&R[((ix  * NRES + iy1) * NRES) + iz1], v * wx0 * ty  * tz );
    atomicAdd(&R[((ix1 * NRES + iy ) * NRES) + iz ], v * tx  * wy0 * wz0);
    atomicAdd(&R[((ix1 * NRES + iy ) * NRES) + iz1], v * tx  * wy0 * tz );
    atomicAdd(&R[((ix1 * NRES + iy1) * NRES) + iz ], v * tx  * ty  * wz0);
    atomicAdd(&R[((ix1 * NRES + iy1) * NRES) + iz1], v * tx  * ty  * tz );
}

// ---------------------------------------------------------------------------
// Forward z FFT (r2c), radix-16 register version. 16 lines/block (contiguous).
// mulz!=0: fuse multiply by -i*wz (wz = 2*pi*k) at stage-out (z channel).
// zeroR!=0: after staging R into LDS, store zeros back to the same addresses
// (thread-local, block-local) — replaces a separate 67 MB hipMemsetAsync so
// the next raster pass finds a cleared grid.
// ---------------------------------------------------------------------------
__global__ __launch_bounds__(256) void kfft_z_r2c(float* __restrict__ R,
                                                  float2* __restrict__ S,
                                                  int mulz, int zeroR) {
    __shared__ float2 Jb[4096];   // 32 KB, multi-purpose
    const int tl = threadIdx.x & 15;
    const int tx = threadIdx.x >> 4;
    const size_t lb = (size_t)blockIdx.x * 16;

    // stage-in: coalesced float4 loads -> padded LDS real array [16][257]
    float* Rf = (float*)Jb;
    float4* rg = (float4*)(R + lb * NRES);
#pragma unroll
    for (int k = 0; k < 4; ++k) {
        int q = threadIdx.x + k * 256;     // float4 id 0..1023
        float4 f = rg[q];
        int i = q >> 6;
        int z = (q & 63) << 2;
        Rf[i * 257 + z + 0] = f.x;
        Rf[i * 257 + z + 1] = f.y;
        Rf[i * 257 + z + 2] = f.z;
        Rf[i * 257 + z + 3] = f.w;
    }
    if (zeroR) {
        // zero exactly the addresses this thread just read (program order per
        // lane per address guarantees load-before-store; no cross-block hazard)
        float4 zz = make_float4(0.f, 0.f, 0.f, 0.f);
#pragma unroll
        for (int k = 0; k < 4; ++k) rg[threadIdx.x + k * 256] = zz;
    }
    __syncthreads();
    float2 v[16];
#pragma unroll
    for (int j = 0; j < 16; ++j)
        v[j] = make_float2(Rf[tl * 257 + tx + 16 * j], 0.f);
    __syncthreads();
    dft16(v, -1.f);
    twiddle_store(Jb, v, tl, tx, -1.f);
    __syncthreads();
    float2 u[16];
#pragma unroll
    for (int j2 = 0; j2 < 16; ++j2) u[j2] = Jb[(tx * 16 + j2) * 16 + tl];
    dft16(u, -1.f);
    __syncthreads();
    // stage-out: keep k<=128, padded [16][131], then coalesced stores
    float2* XL = Jb;
#pragma unroll
    for (int d = 0; d < 16; ++d) {
        int k = tx + 16 * d;
        if (k <= 128) {
            float2 a = u[d];
            if (mulz) {
                float w = TWO_PI * (float)k;
                a = make_float2(w * a.y, -w * a.x);   // -i*w*a
            }
            XL[tl * 131 + k] = a;
        }
    }
    __syncthreads();
    float2* sg = S + lb * NZK;
#pragma unroll
    for (int j = 0; j < 9; ++j) {
        int q = threadIdx.x + j * 256;
        if (q < 16 * NZK) {
            int i = q / NZK;
            int k = q - i * NZK;
            sg[q] = XL[i * 131 + k];
        }
    }
}

// ---------------------------------------------------------------------------
// y FFT (both directions), radix-16 register version, 32-line tiles.
// Lines along y at element stride NZK; tile = 32 consecutive zk (tail masked).
// 512 threads: tl = zk-in-tile (32), tx = position group (16).
// Masked dead lanes in the last zk-group are free (R6/R7 lesson).
// ---------------------------------------------------------------------------
__global__ __launch_bounds__(512) void kfft_y(float2* __restrict__ S, float sgn) {
    __shared__ float2 Jb[8192];   // 64 KB
    const int tl = threadIdx.x & 31;
    const int tx = threadIdx.x >> 5;
    const int xpl = blockIdx.x / 5;
    const int g = blockIdx.x % 5;
    const int zk = g * 32 + tl;
    const bool valid = zk < NZK;
    const size_t base = (size_t)xpl * STRX + (valid ? zk : 128);

    float2 v[16];
#pragma unroll
    for (int j = 0; j < 16; ++j) {
        int y = tx + 16 * j;
        v[j] = valid ? S[base + (size_t)y * NZK] : make_float2(0.f, 0.f);
    }
    dft16(v, sgn);
    twiddle_store32(Jb, v, tl, tx, sgn);
    __syncthreads();
    float2 u[16];
#pragma unroll
    for (int j2 = 0; j2 < 16; ++j2) u[j2] = Jb[(tx * 16 + j2) * 32 + tl];
    dft16(u, sgn);
#pragma unroll
    for (int d = 0; d < 16; ++d) {
        int y = tx + 16 * d;
        if (valid) S[base + (size_t)y * NZK] = u[d];
    }
}

// ---------------------------------------------------------------------------
// Combined forward y FFT of TWO channels with spectral-derivative fusion:
//   A = Fy(A) + (-i*wy) * Fy(B)
// A holds the z-channel spectrum (with -i*wz already applied at z-FFT),
// B holds the y-channel spectrum. Result (partial DivN) written to A in-place.
// 32-line tiles, 512 threads.
// ---------------------------------------------------------------------------
__global__ __launch_bounds__(512) void kfft_y2(float2* __restrict__ A,
                                               const float2* __restrict__ B) {
    __shared__ float2 Jb[8192];
    const int tl = threadIdx.x & 31;
    const int tx = threadIdx.x >> 5;
    const int xpl = blockIdx.x / 5;
    const int g = blockIdx.x % 5;
    const int zk = g * 32 + tl;
    const bool valid = zk < NZK;
    const size_t base = (size_t)xpl * STRX + (valid ? zk : 128);

    float2 vA[16], vB[16];
#pragma unroll
    for (int j = 0; j < 16; ++j) {
        size_t addr = base + (size_t)(tx + 16 * j) * NZK;
        vA[j] = valid ? A[addr] : make_float2(0.f, 0.f);
        vB[j] = valid ? B[addr] : make_float2(0.f, 0.f);
    }
    // pipeline A (z-channel term, derivative already applied)
    dft16(vA, -1.f);
    twiddle_store32(Jb, vA, tl, tx, -1.f);
    __syncthreads();
    float2 uA[16];
#pragma unroll
    for (int j2 = 0; j2 < 16; ++j2) uA[j2] = Jb[(tx * 16 + j2) * 32 + tl];
    dft16(uA, -1.f);
    __syncthreads();
    // pipeline B (y-channel)
    dft16(vB, -1.f);
    twiddle_store32(Jb, vB, tl, tx, -1.f);
    __syncthreads();
    float2 uB[16];
#pragma unroll
    for (int j2 = 0; j2 < 16; ++j2) uB[j2] = Jb[(tx * 16 + j2) * 32 + tl];
    dft16(uB, -1.f);
    // combine: A = uA + (-i*wy)*uB
#pragma unroll
    for (int d = 0; d < 16; ++d) {
        int y = tx + 16 * d;
        float wy = TWO_PI * (float)(y < 128 ? y : y - 256);
        float2 a = uA[d], b = uB[d];
        a.x += wy * b.y;
        a.y -= wy * b.x;
        if (valid) A[base + (size_t)y * NZK] = a;
    }
}

// ---------------------------------------------------------------------------
// Mega x kernel: forward x FFT of A (=Fy-combined y/z terms) and B (=x channel),
// spectral combine D = Fx(A) + (-i*wx)*Fx(B), Poisson solve
// Phi = D * invN3 / (Lap + 1e-6) (DC zeroed), then INVERSE x FFT, write A.
// 16-line tiles, 256 threads, 32 KB LDS (5 blocks/CU: latency-bound kernel,
// occupancy matters more than access granule — measured round 2).
// ---------------------------------------------------------------------------
__global__ __launch_bounds__(256) void kfft_x_mega(float2* __restrict__ A,
                                                   const float2* __restrict__ B) {
    __shared__ float2 Jb[4096];
    const int tl = threadIdx.x & 15;
    const int tx = threadIdx.x >> 4;
    const int l = blockIdx.x * 16 + tl;
    const int y = l / NZK;
    const int zk = l - y * NZK;
    const float fy = (float)(y < 128 ? y : y - 256);
    const float fz = (float)zk;
    const float w2 = TWO_PI * TWO_PI;
    const float invN3 = 1.0f / 16777216.0f;

    float2 vA[16], vB[16];
#pragma unroll
    for (int j = 0; j < 16; ++j) {
        size_t addr = (size_t)(tx + 16 * j) * STRX + l;
        vA[j] = A[addr];
        vB[j] = B[addr];
    }
    // forward pipeline on A
    dft16(vA, -1.f);
    twiddle_store(Jb, vA, tl, tx, -1.f);
    __syncthreads();
    float2 uT[16];
#pragma unroll
    for (int j2 = 0; j2 < 16; ++j2) uT[j2] = Jb[(tx * 16 + j2) * 16 + tl];
    dft16(uT, -1.f);
    __syncthreads();
    // forward pipeline on B
    dft16(vB, -1.f);
    twiddle_store(Jb, vB, tl, tx, -1.f);
    __syncthreads();
    float2 uX[16];
#pragma unroll
    for (int j2 = 0; j2 < 16; ++j2) uX[j2] = Jb[(tx * 16 + j2) * 16 + tl];
    dft16(uX, -1.f);
    __syncthreads();
    // spectral combine + Poisson solve; thread holds spectrum at xk = tx+16d,
    // which is exactly the input layout the inverse pipeline expects.
    float2 s[16];
#pragma unroll
    for (int d = 0; d < 16; ++d) {
        int xk = tx + 16 * d;
        float fx = (float)(xk < 128 ? xk : xk - 256);
        float wx = TWO_PI * fx;
        float2 a = uT[d], b = uX[d];
        a.x += wx * b.y;                       // + (-i*wx)*b
        a.y -= wx * b.x;
        float lap = -(fx * fx + fy * fy + fz * fz) * w2;
        float scale = (xk == 0 && l == 0) ? 0.0f : (invN3 / (lap + 1e-6f));
        s[d] = make_float2(a.x * scale, a.y * scale);
    }
    // inverse x FFT
    dft16(s, 1.f);
    twiddle_store(Jb, s, tl, tx, 1.f);
    __syncthreads();
    float2 u[16];
#pragma unroll
    for (int j2 = 0; j2 < 16; ++j2) u[j2] = Jb[(tx * 16 + j2) * 16 + tl];
    dft16(u, 1.f);
#pragma unroll
    for (int d = 0; d < 16; ++d)
        A[(size_t)(tx + 16 * d) * STRX + l] = u[d];
}

// ---------------------------------------------------------------------------
// Inverse z FFT (c2r): Hermitian extension in registers, coalesced in/out.
// ---------------------------------------------------------------------------
__global__ __launch_bounds__(256) void kfft_z_c2r(const float2* __restrict__ S,
                                                  float* __restrict__ out) {
    __shared__ float2 Jb[4096];
    const int tl = threadIdx.x & 15;
    const int tx = threadIdx.x >> 4;
    const size_t lb = (size_t)blockIdx.x * 16;

    // stage-in: coalesced loads of 16 lines x 129 -> padded LDS [16][131]
    float2* SL = Jb;
    const float2* sg = S + lb * NZK;
#pragma unroll
    for (int j = 0; j < 9; ++j) {
        int q = threadIdx.x + j * 256;
        if (q < 16 * NZK) {
            int i = q / NZK;
            int k = q - i * NZK;
            SL[i * 131 + k] = sg[q];
        }
    }
    __syncthreads();
    float2 v[16];
#pragma unroll
    for (int j = 0; j < 16; ++j) {
        int z = tx + 16 * j;
        if (z <= 128) {
            v[j] = SL[tl * 131 + z];
        } else {
            float2 a = SL[tl * 131 + (256 - z)];
            v[j] = make_float2(a.x, -a.y);
        }
    }
    __syncthreads();
    dft16(v, 1.f);
    twiddle_store(Jb, v, tl, tx, 1.f);
    __syncthreads();
    float2 u[16];
#pragma unroll
    for (int j2 = 0; j2 < 16; ++j2) u[j2] = Jb[(tx * 16 + j2) * 16 + tl];
    dft16(u, 1.f);
    __syncthreads();
    // stage-out real part -> padded [16][257] -> coalesced float4 stores
    float* Xr = (float*)Jb;
#pragma unroll
    for (int d = 0; d < 16; ++d)
        Xr[tl * 257 + tx + 16 * d] = u[d].x;
    __syncthreads();
    float4* og = (float4*)(out + lb * NRES);
#pragma unroll
    for (int k = 0; k < 4; ++k) {
        int q = threadIdx.x + k * 256;
        int i = q >> 6;
        int z = (q & 63) << 2;
        og[q] = make_float4(Xr[i * 257 + z + 0], Xr[i * 257 + z + 1],
                            Xr[i * 257 + z + 2], Xr[i * 257 + z + 3]);
    }
}

// ---------------------------------------------------------------------------
// grid_interp + block-reduced sum of fv; wsS[0] += sum, wsS[1] = phi[0,0,0]
// Reads the ORIGINAL (unsorted) V — the sorted copy in `out` is dead by now.
// ---------------------------------------------------------------------------
__global__ void kinterp(const float* __restrict__ pts, const float* __restrict__ phi,
                        float* __restrict__ wsS, int P) {
    int p = blockIdx.x * blockDim.x + threadIdx.x;
    float fv = 0.0f;
    if (p < P) {
        float px = pts[p * 3 + 0] * (float)NRES;
        float py = pts[p * 3 + 1] * (float)NRES;
        float pz = pts[p * 3 + 2] * (float)NRES;
        float fx0 = floorf(px), fy0 = floorf(py), fz0 = floorf(pz);
        int ix = ((int)fx0) & 255, iy = ((int)fy0) & 255, iz = ((int)fz0) & 255;
        float tx = px - fx0, ty = py - fy0, tz = pz - fz0;
        int ix1 = (ix + 1) & 255, iy1 = (iy + 1) & 255, iz1 = (iz + 1) & 255;
        float wx0 = 1.f - tx, wy0 = 1.f - ty, wz0 = 1.f - tz;
        fv =  phi[((ix  * NRES + iy ) * NRES) + iz ] * wx0 * wy0 * wz0
            + phi[((ix  * NRES + iy ) * NRES) + iz1] * wx0 * wy0 * tz
            + phi[((ix  * NRES + iy1) * NRES) + iz ] * wx0 * ty  * wz0
            + phi[((ix  * NRES + iy1) * NRES) + iz1] * wx0 * ty  * tz
            + phi[((ix1 * NRES + iy ) * NRES) + iz ] * tx  * wy0 * wz0
            + phi[((ix1 * NRES + iy ) * NRES) + iz1] * tx  * wy0 * tz
            + phi[((ix1 * NRES + iy1) * NRES) + iz ] * tx  * ty  * wz0
            + phi[((ix1 * NRES + iy1) * NRES) + iz1] * tx  * ty  * tz;
    }
#pragma unroll
    for (int off = 32; off > 0; off >>= 1) fv += __shfl_down(fv, off);
    __shared__ float wsum[4];
    int lane = threadIdx.x & 63, wid = threadIdx.x >> 6;
    if (lane == 0) wsum[wid] = fv;
    __syncthreads();
    if (threadIdx.x == 0) {
        float t = 0.0f;
        for (int i = 0; i < (int)(blockDim.x >> 6); ++i) t += wsum[i];
        atomicAdd(&wsS[0], t);
    }
    if (blockIdx.x == 0 && threadIdx.x == 0) wsS[1] = phi[0];
}

// ---------------------------------------------------------------------------
// out = -(phi - offset) * 0.5 / |phi000 - offset|, float4 vectorized
// ---------------------------------------------------------------------------
__global__ void kfinal(float4* __restrict__ out, const float* __restrict__ wsS, float invP) {
    int idx = blockIdx.x * blockDim.x + threadIdx.x;
    float offset = wsS[0] * invP;
    float fv0 = wsS[1] - offset;
    float sc = -0.5f / fabsf(fv0);
    float4 o = out[idx];
    o.x = (o.x - offset) * sc;
    o.y = (o.y - offset) * sc;
    o.z = (o.z - offset) * sc;
    o.w = (o.w - offset) * sc;
    out[idx] = o;
}

extern "C" void kernel_launch(void* const* d_in, const int* in_sizes, int n_in,
                              void* d_out, int out_size, void* d_ws, size_t ws_size,
                              hipStream_t stream) {
    const float* V = (const float*)d_in[0];
    const float* N = (const float*)d_in[1];
    float* out = (float*)d_out;
    const int P = in_sizes[0] / 3;   // 100000

    float2* A = (float2*)d_ws;                    // NSPEC float2 (accumulator / result)
    float2* B = A + NSPEC;                        // NSPEC float2 (per-channel spectrum)
    float*  R = (float*)(B + NSPEC);              // 256^3 floats (real scratch)
    float*  wsS = R + (size_t)NRES * NRES * NRES; // 2 scalars

    // sort scratch lives in `out` — valid only until kfft_z_c2r overwrites out;
    // used by the three rasters, NOT by kinterp (round-9 lifetime bug).
    int*   hist  = (int*)out;             // NBIN
    int*   offs  = hist + NBIN;           // NBIN
    float* spts  = (float*)(offs + NBIN); // 3*P
    float* svals = spts + 3 * P;          // 3*P

    const int rasterBlocks = (P + 255) / 256;
    const int zBlocks = NLINE_XY / 16;   // 4096
    const int yBlocks = NRES * 5;        // 1280 (32-wide zk tiles)
    const int xBlocks = STRX / 16;       // 2064 (16-wide l tiles)

    // ---- spatial sort of the point cloud (counting sort by (ix,iy)) ----
    hipMemsetAsync(hist, 0, NBIN * sizeof(int), stream);
    khist<<<rasterBlocks, 256, 0, stream>>>(V, hist, P);
    kscan<<<1, 1024, 0, stream>>>(hist, offs);
    kscatter<<<rasterBlocks, 256, 0, stream>>>(V, N, offs, spts, svals, P);

    // channel z -> A, with -i*wz fused into the z-FFT output; z-FFT re-zeroes R
    hipMemsetAsync(R, 0, (size_t)NRES * NRES * NRES * sizeof(float), stream);
    kraster<<<rasterBlocks, 256, 0, stream>>>(spts, svals, R, P, 2);
    kfft_z_r2c<<<zBlocks, 256, 0, stream>>>(R, A, 1, 1);

    // channel y -> B; z-FFT re-zeroes R for the x-channel raster
    kraster<<<rasterBlocks, 256, 0, stream>>>(spts, svals, R, P, 1);
    kfft_z_r2c<<<zBlocks, 256, 0, stream>>>(R, B, 0, 1);

    // A = Fy(A) + (-i*wy)*Fy(B)   (partial DivN, x-FFT pending)
    kfft_y2<<<yBlocks, 512, 0, stream>>>(A, B);

    // channel x -> B, then its forward y-FFT (no re-zero needed afterwards)
    kraster<<<rasterBlocks, 256, 0, stream>>>(spts, svals, R, P, 0);
    kfft_z_r2c<<<zBlocks, 256, 0, stream>>>(R, B, 0, 0);
    kfft_y<<<yBlocks, 512, 0, stream>>>(B, -1.0f);

    // forward x on A and B, combine with -i*wx, Poisson solve, inverse x
    kfft_x_mega<<<xBlocks, 256, 0, stream>>>(A, B);

    // inverse y and z  (kfft_z_c2r overwrites the sort scratch in `out`)
    kfft_y<<<yBlocks, 512, 0, stream>>>(A, +1.0f);
    kfft_z_c2r<<<zBlocks, 256, 0, stream>>>(A, out);

    hipMemsetAsync(wsS, 0, 2 * sizeof(float), stream);
    kinterp<<<rasterBlocks, 256, 0, stream>>>(V, out, wsS, P);
    kfinal<<<NLINE_XY / 4, 256, 0, stream>>>((float4*)out, wsS, 1.0f / (float)P);
}

// Round 11
// 453.608 us; speedup vs baseline: 1.0898x; 1.0898x over previous
//
#include <hip/hip_runtime.h>
#include <math.h>

#define NRES 256
#define NZK  129                   // NRES/2 + 1
#define NLINE_XY (NRES * NRES)     // 65536 z-lines
#define STRX (NRES * NZK)          // 33024 : float2 stride between x-planes
#define NSPEC (NRES * NRES * NZK)  // 8454144 spectral elements
#define TWO_PI 6.283185307179586f

// ---------------------------------------------------------------------------
// 16-point DFT in registers, radix-2 Stockham, fully unrolled.
// y[c] = sum_j v[j] * e^{sgn*2*pi*i*j*c/16}. Result in v, natural order.
// ---------------------------------------------------------------------------
__device__ __forceinline__ void dft16(float2* v, float sgn) {
    const float C16[8] = {1.f, 0.923879532511287f, 0.707106781186548f, 0.382683432365090f,
                          0.f, -0.382683432365090f, -0.707106781186548f, -0.923879532511287f};
    const float S16[8] = {0.f, 0.382683432365090f, 0.707106781186548f, 0.923879532511287f,
                          1.f, 0.923879532511287f, 0.707106781186548f, 0.382683432365090f};
    float2 t[16];
    float2* src = v;
    float2* dst = t;
#pragma unroll
    for (int s = 0; s < 4; ++s) {
        const int st = 1 << s;
#pragma unroll
        for (int bb = 0; bb < 8; ++bb) {
            const int q = bb & (st - 1);
            const int p = bb >> s;
            const int m = p << s;               // twiddle index into C16/S16
            float2 a = src[q + st * p];
            float2 b = src[q + st * p + 8];     // st*(p + nt/2) = st*p + 8
            float cw = C16[m], sw = sgn * S16[m];
            float ar = a.x - b.x, ai = a.y - b.y;
            dst[q + st * 2 * p]       = make_float2(a.x + b.x, a.y + b.y);
            dst[q + st * (2 * p + 1)] = make_float2(ar * cw - ai * sw, ar * sw + ai * cw);
        }
        float2* tmp = src; src = dst; dst = tmp;
    }
    // 4 stages (even) -> result back in v
}

// 16-wide tile variant (z/x kernels): J[c][tx][tl], tl in [0,16)
__device__ __forceinline__ void twiddle_store(float2* J, const float2* v, int tl, int tx, float sgn) {
    float s1, c1;
    __sincosf(sgn * (TWO_PI / 256.f) * (float)tx, &s1, &c1);
    float wr = 1.f, wi = 0.f;
#pragma unroll
    for (int c = 0; c < 16; ++c) {
        float2 a = v[c];
        J[(c * 16 + tx) * 16 + tl] = make_float2(a.x * wr - a.y * wi, a.x * wi + a.y * wr);
        float nwr = wr * c1 - wi * s1;
        wi = wr * s1 + wi * c1;
        wr = nwr;
    }
}

// 32-wide tile variant (y kernels): J[c][tx][tl], tl in [0,32)
__device__ __forceinline__ void twiddle_store32(float2* J, const float2* v, int tl, int tx, float sgn) {
    float s1, c1;
    __sincosf(sgn * (TWO_PI / 256.f) * (float)tx, &s1, &c1);
    float wr = 1.f, wi = 0.f;
#pragma unroll
    for (int c = 0; c < 16; ++c) {
        float2 a = v[c];
        J[(c * 16 + tx) * 32 + tl] = make_float2(a.x * wr - a.y * wi, a.x * wi + a.y * wr);
        float nwr = wr * c1 - wi * s1;
        wi = wr * s1 + wi * c1;
        wr = nwr;
    }
}

// ---------------------------------------------------------------------------
// Rasterize channel c into real grid R. Scattered atomics are L3-resident
// (67 MB grid < 256 MB Infinity Cache) — spatial sort was a net loss (R10).
// ---------------------------------------------------------------------------
__global__ void kraster(const float* __restrict__ pts, const float* __restrict__ vals,
                        float* __restrict__ R, int P, int c) {
    int p = blockIdx.x * blockDim.x + threadIdx.x;
    if (p >= P) return;
    float px = pts[p * 3 + 0] * (float)NRES;
    float py = pts[p * 3 + 1] * (float)NRES;
    float pz = pts[p * 3 + 2] * (float)NRES;
    float fx0 = floorf(px), fy0 = floorf(py), fz0 = floorf(pz);
    int ix = ((int)fx0) & 255, iy = ((int)fy0) & 255, iz = ((int)fz0) & 255;
    float tx = px - fx0, ty = py - fy0, tz = pz - fz0;
    float v = vals[p * 3 + c];
    int ix1 = (ix + 1) & 255, iy1 = (iy + 1) & 255, iz1 = (iz + 1) & 255;
    float wx0 = 1.f - tx, wy0 = 1.f - ty, wz0 = 1.f - tz;
    atomicAdd(&R[((ix  * NRES + iy ) * NRES) + iz ], v * wx0 * wy0 * wz0);
    atomicAdd(&R[((ix  * NRES + iy ) * NRES) + iz1], v * wx0 * wy0 * tz );
    atomicAdd(&R[((ix  * NRES + iy1) * NRES) + iz ], v * wx0 * ty  * wz0);
    atomicAdd(&R[((ix  * NRES + iy1) * NRES) + iz1], v * wx0 * ty  * tz );
    atomicAdd(&R[((ix1 * NRES + iy ) * NRES) + iz ], v * tx  * wy0 * wz0);
    atomicAdd(&R[((ix1 * NRES + iy ) * NRES) + iz1], v * tx  * wy0 * tz );
    atomicAdd(&R[((ix1 * NRES + iy1) * NRES) + iz ], v * tx  * ty  * wz0);
    atomicAdd(&R[((ix1 * NRES + iy1) * NRES) + iz1], v * tx  * ty  * tz );
}

// ---------------------------------------------------------------------------
// Forward z FFT (r2c), radix-16 register version. 16 lines/block (contiguous).
// mulz!=0: fuse multiply by -i*wz (wz = 2*pi*k) at stage-out (z channel).
// zeroR!=0: after staging R into LDS, store zeros back to the same addresses
// (thread-local, block-local) — replaces a separate 67 MB hipMemsetAsync so
// the next raster pass finds a cleared grid.
// ---------------------------------------------------------------------------
__global__ __launch_bounds__(256) void kfft_z_r2c(float* __restrict__ R,
                                                  float2* __restrict__ S,
                                                  int mulz, int zeroR) {
    __shared__ float2 Jb[4096];   // 32 KB, multi-purpose
    const int tl = threadIdx.x & 15;
    const int tx = threadIdx.x >> 4;
    const size_t lb = (size_t)blockIdx.x * 16;

    // stage-in: coalesced float4 loads -> padded LDS real array [16][257]
    float* Rf = (float*)Jb;
    float4* rg = (float4*)(R + lb * NRES);
#pragma unroll
    for (int k = 0; k < 4; ++k) {
        int q = threadIdx.x + k * 256;     // float4 id 0..1023
        float4 f = rg[q];
        int i = q >> 6;
        int z = (q & 63) << 2;
        Rf[i * 257 + z + 0] = f.x;
        Rf[i * 257 + z + 1] = f.y;
        Rf[i * 257 + z + 2] = f.z;
        Rf[i * 257 + z + 3] = f.w;
    }
    if (zeroR) {
        // zero exactly the addresses this thread just read (program order per
        // lane per address guarantees load-before-store; no cross-block hazard)
        float4 zz = make_float4(0.f, 0.f, 0.f, 0.f);
#pragma unroll
        for (int k = 0; k < 4; ++k) rg[threadIdx.x + k * 256] = zz;
    }
    __syncthreads();
    float2 v[16];
#pragma unroll
    for (int j = 0; j < 16; ++j)
        v[j] = make_float2(Rf[tl * 257 + tx + 16 * j], 0.f);
    __syncthreads();
    dft16(v, -1.f);
    twiddle_store(Jb, v, tl, tx, -1.f);
    __syncthreads();
    float2 u[16];
#pragma unroll
    for (int j2 = 0; j2 < 16; ++j2) u[j2] = Jb[(tx * 16 + j2) * 16 + tl];
    dft16(u, -1.f);
    __syncthreads();
    // stage-out: keep k<=128, padded [16][131], then coalesced stores
    float2* XL = Jb;
#pragma unroll
    for (int d = 0; d < 16; ++d) {
        int k = tx + 16 * d;
        if (k <= 128) {
            float2 a = u[d];
            if (mulz) {
                float w = TWO_PI * (float)k;
                a = make_float2(w * a.y, -w * a.x);   // -i*w*a
            }
            XL[tl * 131 + k] = a;
        }
    }
    __syncthreads();
    float2* sg = S + lb * NZK;
#pragma unroll
    for (int j = 0; j < 9; ++j) {
        int q = threadIdx.x + j * 256;
        if (q < 16 * NZK) {
            int i = q / NZK;
            int k = q - i * NZK;
            sg[q] = XL[i * 131 + k];
        }
    }
}

// ---------------------------------------------------------------------------
// y FFT (both directions), radix-16 register version, 32-line tiles.
// Lines along y at element stride NZK; tile = 32 consecutive zk (tail masked).
// 512 threads: tl = zk-in-tile (32), tx = position group (16).
// Masked dead lanes in the last zk-group are free (R6/R7 lesson).
// ---------------------------------------------------------------------------
__global__ __launch_bounds__(512) void kfft_y(float2* __restrict__ S, float sgn) {
    __shared__ float2 Jb[8192];   // 64 KB
    const int tl = threadIdx.x & 31;
    const int tx = threadIdx.x >> 5;
    const int xpl = blockIdx.x / 5;
    const int g = blockIdx.x % 5;
    const int zk = g * 32 + tl;
    const bool valid = zk < NZK;
    const size_t base = (size_t)xpl * STRX + (valid ? zk : 128);

    float2 v[16];
#pragma unroll
    for (int j = 0; j < 16; ++j) {
        int y = tx + 16 * j;
        v[j] = valid ? S[base + (size_t)y * NZK] : make_float2(0.f, 0.f);
    }
    dft16(v, sgn);
    twiddle_store32(Jb, v, tl, tx, sgn);
    __syncthreads();
    float2 u[16];
#pragma unroll
    for (int j2 = 0; j2 < 16; ++j2) u[j2] = Jb[(tx * 16 + j2) * 32 + tl];
    dft16(u, sgn);
#pragma unroll
    for (int d = 0; d < 16; ++d) {
        int y = tx + 16 * d;
        if (valid) S[base + (size_t)y * NZK] = u[d];
    }
}

// ---------------------------------------------------------------------------
// Combined forward y FFT of TWO channels with spectral-derivative fusion:
//   A = Fy(A) + (-i*wy) * Fy(B)
// A holds the z-channel spectrum (with -i*wz already applied at z-FFT),
// B holds the y-channel spectrum. Result (partial DivN) written to A in-place.
// 32-line tiles, 512 threads.
// ---------------------------------------------------------------------------
__global__ __launch_bounds__(512) void kfft_y2(float2* __restrict__ A,
                                               const float2* __restrict__ B) {
    __shared__ float2 Jb[8192];
    const int tl = threadIdx.x & 31;
    const int tx = threadIdx.x >> 5;
    const int xpl = blockIdx.x / 5;
    const int g = blockIdx.x % 5;
    const int zk = g * 32 + tl;
    const bool valid = zk < NZK;
    const size_t base = (size_t)xpl * STRX + (valid ? zk : 128);

    float2 vA[16], vB[16];
#pragma unroll
    for (int j = 0; j < 16; ++j) {
        size_t addr = base + (size_t)(tx + 16 * j) * NZK;
        vA[j] = valid ? A[addr] : make_float2(0.f, 0.f);
        vB[j] = valid ? B[addr] : make_float2(0.f, 0.f);
    }
    // pipeline A (z-channel term, derivative already applied)
    dft16(vA, -1.f);
    twiddle_store32(Jb, vA, tl, tx, -1.f);
    __syncthreads();
    float2 uA[16];
#pragma unroll
    for (int j2 = 0; j2 < 16; ++j2) uA[j2] = Jb[(tx * 16 + j2) * 32 + tl];
    dft16(uA, -1.f);
    __syncthreads();
    // pipeline B (y-channel)
    dft16(vB, -1.f);
    twiddle_store32(Jb, vB, tl, tx, -1.f);
    __syncthreads();
    float2 uB[16];
#pragma unroll
    for (int j2 = 0; j2 < 16; ++j2) uB[j2] = Jb[(tx * 16 + j2) * 32 + tl];
    dft16(uB, -1.f);
    // combine: A = uA + (-i*wy)*uB
#pragma unroll
    for (int d = 0; d < 16; ++d) {
        int y = tx + 16 * d;
        float wy = TWO_PI * (float)(y < 128 ? y : y - 256);
        float2 a = uA[d], b = uB[d];
        a.x += wy * b.y;
        a.y -= wy * b.x;
        if (valid) A[base + (size_t)y * NZK] = a;
    }
}

// ---------------------------------------------------------------------------
// Mega x kernel: forward x FFT of A (=Fy-combined y/z terms) and B (=x channel),
// spectral combine D = Fx(A) + (-i*wx)*Fx(B), Poisson solve
// Phi = D * invN3 / (Lap + 1e-6) (DC zeroed), then INVERSE x FFT, write A.
// 16-line tiles, 256 threads, 32 KB LDS (5 blocks/CU: latency-bound kernel,
// occupancy matters more than access granule — measured round 2).
// ---------------------------------------------------------------------------
__global__ __launch_bounds__(256) void kfft_x_mega(float2* __restrict__ A,
                                                   const float2* __restrict__ B) {
    __shared__ float2 Jb[4096];
    const int tl = threadIdx.x & 15;
    const int tx = threadIdx.x >> 4;
    const int l = blockIdx.x * 16 + tl;
    const int y = l / NZK;
    const int zk = l - y * NZK;
    const float fy = (float)(y < 128 ? y : y - 256);
    const float fz = (float)zk;
    const float w2 = TWO_PI * TWO_PI;
    const float invN3 = 1.0f / 16777216.0f;

    float2 vA[16], vB[16];
#pragma unroll
    for (int j = 0; j < 16; ++j) {
        size_t addr = (size_t)(tx + 16 * j) * STRX + l;
        vA[j] = A[addr];
        vB[j] = B[addr];
    }
    // forward pipeline on A
    dft16(vA, -1.f);
    twiddle_store(Jb, vA, tl, tx, -1.f);
    __syncthreads();
    float2 uT[16];
#pragma unroll
    for (int j2 = 0; j2 < 16; ++j2) uT[j2] = Jb[(tx * 16 + j2) * 16 + tl];
    dft16(uT, -1.f);
    __syncthreads();
    // forward pipeline on B
    dft16(vB, -1.f);
    twiddle_store(Jb, vB, tl, tx, -1.f);
    __syncthreads();
    float2 uX[16];
#pragma unroll
    for (int j2 = 0; j2 < 16; ++j2) uX[j2] = Jb[(tx * 16 + j2) * 16 + tl];
    dft16(uX, -1.f);
    __syncthreads();
    // spectral combine + Poisson solve; thread holds spectrum at xk = tx+16d,
    // which is exactly the input layout the inverse pipeline expects.
    float2 s[16];
#pragma unroll
    for (int d = 0; d < 16; ++d) {
        int xk = tx + 16 * d;
        float fx = (float)(xk < 128 ? xk : xk - 256);
        float wx = TWO_PI * fx;
        float2 a = uT[d], b = uX[d];
        a.x += wx * b.y;                       // + (-i*wx)*b
        a.y -= wx * b.x;
        float lap = -(fx * fx + fy * fy + fz * fz) * w2;
        float scale = (xk == 0 && l == 0) ? 0.0f : (invN3 / (lap + 1e-6f));
        s[d] = make_float2(a.x * scale, a.y * scale);
    }
    // inverse x FFT
    dft16(s, 1.f);
    twiddle_store(Jb, s, tl, tx, 1.f);
    __syncthreads();
    float2 u[16];
#pragma unroll
    for (int j2 = 0; j2 < 16; ++j2) u[j2] = Jb[(tx * 16 + j2) * 16 + tl];
    dft16(u, 1.f);
#pragma unroll
    for (int d = 0; d < 16; ++d)
        A[(size_t)(tx + 16 * d) * STRX + l] = u[d];
}

// ---------------------------------------------------------------------------
// Inverse z FFT (c2r): Hermitian extension in registers, coalesced in/out.
// ---------------------------------------------------------------------------
__global__ __launch_bounds__(256) void kfft_z_c2r(const float2* __restrict__ S,
                                                  float* __restrict__ out) {
    __shared__ float2 Jb[4096];
    const int tl = threadIdx.x & 15;
    const int tx = threadIdx.x >> 4;
    const size_t lb = (size_t)blockIdx.x * 16;

    // stage-in: coalesced loads of 16 lines x 129 -> padded LDS [16][131]
    float2* SL = Jb;
    const float2* sg = S + lb * NZK;
#pragma unroll
    for (int j = 0; j < 9; ++j) {
        int q = threadIdx.x + j * 256;
        if (q < 16 * NZK) {
            int i = q / NZK;
            int k = q - i * NZK;
            SL[i * 131 + k] = sg[q];
        }
    }
    __syncthreads();
    float2 v[16];
#pragma unroll
    for (int j = 0; j < 16; ++j) {
        int z = tx + 16 * j;
        if (z <= 128) {
            v[j] = SL[tl * 131 + z];
        } else {
            float2 a = SL[tl * 131 + (256 - z)];
            v[j] = make_float2(a.x, -a.y);
        }
    }
    __syncthreads();
    dft16(v, 1.f);
    twiddle_store(Jb, v, tl, tx, 1.f);
    __syncthreads();
    float2 u[16];
#pragma unroll
    for (int j2 = 0; j2 < 16; ++j2) u[j2] = Jb[(tx * 16 + j2) * 16 + tl];
    dft16(u, 1.f);
    __syncthreads();
    // stage-out real part -> padded [16][257] -> coalesced float4 stores
    float* Xr = (float*)Jb;
#pragma unroll
    for (int d = 0; d < 16; ++d)
        Xr[tl * 257 + tx + 16 * d] = u[d].x;
    __syncthreads();
    float4* og = (float4*)(out + lb * NRES);
#pragma unroll
    for (int k = 0; k < 4; ++k) {
        int q = threadIdx.x + k * 256;
        int i = q >> 6;
        int z = (q & 63) << 2;
        og[q] = make_float4(Xr[i * 257 + z + 0], Xr[i * 257 + z + 1],
                            Xr[i * 257 + z + 2], Xr[i * 257 + z + 3]);
    }
}

// ---------------------------------------------------------------------------
// grid_interp + block-reduced sum of fv; wsS[0] += sum, wsS[1] = phi[0,0,0]
// ---------------------------------------------------------------------------
__global__ void kinterp(const float* __restrict__ pts, const float* __restrict__ phi,
                        float* __restrict__ wsS, int P) {
    int p = blockIdx.x * blockDim.x + threadIdx.x;
    float fv = 0.0f;
    if (p < P) {
        float px = pts[p * 3 + 0] * (float)NRES;
        float py = pts[p * 3 + 1] * (float)NRES;
        float pz = pts[p * 3 + 2] * (float)NRES;
        float fx0 = floorf(px), fy0 = floorf(py), fz0 = floorf(pz);
        int ix = ((int)fx0) & 255, iy = ((int)fy0) & 255, iz = ((int)fz0) & 255;
        float tx = px - fx0, ty = py - fy0, tz = pz - fz0;
        int ix1 = (ix + 1) & 255, iy1 = (iy + 1) & 255, iz1 = (iz + 1) & 255;
        float wx0 = 1.f - tx, wy0 = 1.f - ty, wz0 = 1.f - tz;
        fv =  phi[((ix  * NRES + iy ) * NRES) + iz ] * wx0 * wy0 * wz0
            + phi[((ix  * NRES + iy ) * NRES) + iz1] * wx0 * wy0 * tz
            + phi[((ix  * NRES + iy1) * NRES) + iz ] * wx0 * ty  * wz0
            + phi[((ix  * NRES + iy1) * NRES) + iz1] * wx0 * ty  * tz
            + phi[((ix1 * NRES + iy ) * NRES) + iz ] * tx  * wy0 * wz0
            + phi[((ix1 * NRES + iy ) * NRES) + iz1] * tx  * wy0 * tz
            + phi[((ix1 * NRES + iy1) * NRES) + iz ] * tx  * ty  * wz0
            + phi[((ix1 * NRES + iy1) * NRES) + iz1] * tx  * ty  * tz;
    }
#pragma unroll
    for (int off = 32; off > 0; off >>= 1) fv += __shfl_down(fv, off);
    __shared__ float wsum[4];
    int lane = threadIdx.x & 63, wid = threadIdx.x >> 6;
    if (lane == 0) wsum[wid] = fv;
    __syncthreads();
    if (threadIdx.x == 0) {
        float t = 0.0f;
        for (int i = 0; i < (int)(blockDim.x >> 6); ++i) t += wsum[i];
        atomicAdd(&wsS[0], t);
    }
    if (blockIdx.x == 0 && threadIdx.x == 0) wsS[1] = phi[0];
}

// ---------------------------------------------------------------------------
// out = -(phi - offset) * 0.5 / |phi000 - offset|, float4 vectorized
// ---------------------------------------------------------------------------
__global__ void kfinal(float4* __restrict__ out, const float* __restrict__ wsS, float invP) {
    int idx = blockIdx.x * blockDim.x + threadIdx.x;
    float offset = wsS[0] * invP;
    float fv0 = wsS[1] - offset;
    float sc = -0.5f / fabsf(fv0);
    float4 o = out[idx];
    o.x = (o.x - offset) * sc;
    o.y = (o.y - offset) * sc;
    o.z = (o.z - offset) * sc;
    o.w = (o.w - offset) * sc;
    out[idx] = o;
}

extern "C" void kernel_launch(void* const* d_in, const int* in_sizes, int n_in,
                              void* d_out, int out_size, void* d_ws, size_t ws_size,
                              hipStream_t stream) {
    const float* V = (const float*)d_in[0];
    const float* N = (const float*)d_in[1];
    float* out = (float*)d_out;
    const int P = in_sizes[0] / 3;   // 100000

    float2* A = (float2*)d_ws;                    // NSPEC float2 (accumulator / result)
    float2* B = A + NSPEC;                        // NSPEC float2 (per-channel spectrum)
    float*  R = (float*)(B + NSPEC);              // 256^3 floats (real scratch)
    float*  wsS = R + (size_t)NRES * NRES * NRES; // 2 scalars

    const int rasterBlocks = (P + 255) / 256;
    const int zBlocks = NLINE_XY / 16;   // 4096
    const int yBlocks = NRES * 5;        // 1280 (32-wide zk tiles)
    const int xBlocks = STRX / 16;       // 2064 (16-wide l tiles)

    // channel z -> A, with -i*wz fused into the z-FFT output; z-FFT re-zeroes R
    hipMemsetAsync(R, 0, (size_t)NRES * NRES * NRES * sizeof(float), stream);
    kraster<<<rasterBlocks, 256, 0, stream>>>(V, N, R, P, 2);
    kfft_z_r2c<<<zBlocks, 256, 0, stream>>>(R, A, 1, 1);

    // channel y -> B; z-FFT re-zeroes R for the x-channel raster
    kraster<<<rasterBlocks, 256, 0, stream>>>(V, N, R, P, 1);
    kfft_z_r2c<<<zBlocks, 256, 0, stream>>>(R, B, 0, 1);

    // A = Fy(A) + (-i*wy)*Fy(B)   (partial DivN, x-FFT pending)
    kfft_y2<<<yBlocks, 512, 0, stream>>>(A, B);

    // channel x -> B, then its forward y-FFT (no re-zero needed afterwards)
    kraster<<<rasterBlocks, 256, 0, stream>>>(V, N, R, P, 0);
    kfft_z_r2c<<<zBlocks, 256, 0, stream>>>(R, B, 0, 0);
    kfft_y<<<yBlocks, 512, 0, stream>>>(B, -1.0f);

    // forward x on A and B, combine with -i*wx, Poisson solve, inverse x
    kfft_x_mega<<<xBlocks, 256, 0, stream>>>(A, B);

    // inverse y and z
    kfft_y<<<yBlocks, 512, 0, stream>>>(A, +1.0f);
    kfft_z_c2r<<<zBlocks, 256, 0, stream>>>(A, out);

    hipMemsetAsync(wsS, 0, 2 * sizeof(float), stream);
    kinterp<<<rasterBlocks, 256, 0, stream>>>(V, out, wsS, P);
    kfinal<<<NLINE_XY / 4, 256, 0, stream>>>((float4*)out, wsS, 1.0f / (float)P);
}